// Round 9
// baseline (324.056 us; speedup 1.0000x reference)
//
#include <hip/hip_runtime.h>
#include <math.h>

// Actor_att1 on gfx950 — R9: wave-specialized branch split.
// Block = 128 (2 waves) per 32-row tile. Both waves stage + self-encode;
// wave0 = food branch + merge MLP, wave1 = other branch (ships Bo via LDS).
// Each branch loop split into even/odd entity chains (softmax sums are
// additive since no running max) -> chain depth 8, 2 chains/wave.
// 32x32x16 MFMA conventions HW-validated in R8 (absmax 1.95e-3).

#define OBS 127
#define XSS 132   // f16 LDS row stride

typedef _Float16 v4h  __attribute__((ext_vector_type(4)));
typedef _Float16 v8h  __attribute__((ext_vector_type(8)));
typedef __fp16   p2h  __attribute__((ext_vector_type(2)));
typedef float    v16f __attribute__((ext_vector_type(16)));
typedef float    f4u  __attribute__((ext_vector_type(4), aligned(4)));

#define MFMA16(a, b, c) __builtin_amdgcn_mfma_f32_32x32x16_f16((a), (b), (c), 0, 0, 0)

union PK8 { p2h p[4]; v8h h; };
union HU8 { unsigned u[4]; v8h h; _Float16 e[8]; };
union BO  { v8h h; uint4 u; };

__device__ __forceinline__ v8h zero8h() {
    v8h z;
    #pragma unroll
    for (int j = 0; j < 8; ++j) z[j] = (_Float16)0.f;
    return z;
}
__device__ __forceinline__ v8h pk8(const v16f& d, int b) {
    PK8 q;
    q.p[0] = __builtin_amdgcn_cvt_pkrtz(d[b],     d[b + 1]);
    q.p[1] = __builtin_amdgcn_cvt_pkrtz(d[b + 2], d[b + 3]);
    q.p[2] = __builtin_amdgcn_cvt_pkrtz(d[b + 4], d[b + 5]);
    q.p[3] = __builtin_amdgcn_cvt_pkrtz(d[b + 6], d[b + 7]);
    return q.h;
}
__device__ __forceinline__ v8h pkr8(const v16f& d, int b) {
    return __builtin_elementwise_max(pk8(d, b), zero8h());
}
__device__ __forceinline__ v8h pk8f(const float (&v)[8]) {
    PK8 q;
    q.p[0] = __builtin_amdgcn_cvt_pkrtz(v[0], v[1]);
    q.p[1] = __builtin_amdgcn_cvt_pkrtz(v[2], v[3]);
    q.p[2] = __builtin_amdgcn_cvt_pkrtz(v[4], v[5]);
    q.p[3] = __builtin_amdgcn_cvt_pkrtz(v[6], v[7]);
    return q.h;
}
__device__ __forceinline__ v8h lrelu8(v8h t) {
    const v8h s = t * (_Float16)0.01f;
    return __builtin_elementwise_max(t, s);
}
// L1 A-frag: output ch permuted by bitswap23(m); bias row at k==kin.
__device__ __forceinline__ v8h a1fragK16(const float* __restrict__ W,
                                         const float* __restrict__ b,
                                         int kin, int m, int h) {
    const int Lm = (m & ~12) | ((m & 4) << 1) | ((m & 8) >> 1);
    v8h r;
    #pragma unroll
    for (int j = 0; j < 8; ++j) {
        const int k = 8 * h + j;
        const float v = (k < kin) ? W[k * 32 + Lm] : (k == kin ? b[Lm] : 0.f);
        r[j] = (_Float16)v;
    }
    return r;
}
// L2 A chunk s: pairs with B logical ch 16s+8h+j (W2 is 32x16).
__device__ __forceinline__ v8h a2fragK16(const float* __restrict__ W2,
                                         int s, int m, int h) {
    v8h r;
    #pragma unroll
    for (int j = 0; j < 8; ++j)
        r[j] = (_Float16)((m < 16) ? W2[(16 * s + 8 * h + j) * 16 + m] : 0.f);
    return r;
}
// merge A chunk: B position (h,j) holds source ch base+(j&3)+8*(j>>2)+4h.
__device__ __forceinline__ v8h mfragK16(const float* __restrict__ W, int ncols,
                                        int base, int m, int h, int colmax) {
    v8h r;
    #pragma unroll
    for (int j = 0; j < 8; ++j) {
        const int ch = base + (j & 3) + 8 * (j >> 2) + 4 * h;
        r[j] = (_Float16)((m < colmax) ? W[ch * ncols + m] : 0.f);
    }
    return r;
}
__device__ __forceinline__ float fast_tanh(float x) {
    x = fminf(fmaxf(x, -15.f), 15.f);
    const float ex = __expf(2.f * x);
    return (ex - 1.f) / (ex + 1.f);
}

// One entity: L1 (1 MFMA) -> relu-pack -> L2 (2 chained) -> softmax acc.
template <int BR>
__device__ __forceinline__ void entity_step(const _Float16* __restrict__ xr,
                                            int e, int h,
                                            v8h A1, v8h A2a, v8h A2b,
                                            const float (&b2v)[8],
                                            const float (&stl)[8],
                                            float& l, float (&o)[8],
                                            v16f z16) {
    v8h bf = zero8h();
    if (h == 0) {
        HU8 u;
        #pragma unroll
        for (int j = 0; j < 4; ++j) u.u[j] = 0;
        if (BR == 1) {
            u.e[0] = xr[79 + 3 * e];
            u.e[1] = xr[80 + 3 * e];
            u.e[2] = xr[81 + 3 * e];
            u.e[3] = (_Float16)1.f;          // k=3 bias feature
        } else {
            u.u[0] = *(const unsigned*)(xr + 4 + 2 * e);    // pos.xy
            u.u[1] = *(const unsigned*)(xr + 34 + 2 * e);   // vel.xy
            u.e[4] = xr[64 + e];             // k=4 scal
            u.e[5] = (_Float16)1.f;          // k=5 bias
        }
        bf = u.h;
    }
    const v16f dH = MFMA16(A1, bf, z16);
    const v8h p0 = pkr8(dH, 0);
    const v8h p1 = pkr8(dH, 8);
    v16f c = MFMA16(A2a, p0, z16);
    c = MFMA16(A2b, p1, c);
    float e2[8], part = 0.f;
    #pragma unroll
    for (int r = 0; r < 8; ++r) {
        e2[r] = fmaxf(c[r] + b2v[r], 0.f);
        part += stl[r] * e2[r];
    }
    part += __shfl_xor(part, 32);
    const float p = __builtin_amdgcn_exp2f(part);
    l += p;
    #pragma unroll
    for (int r = 0; r < 8; ++r) o[r] += p * e2[r];
}

__device__ __forceinline__ v8h ln_fin(float l, const float (&o)[8],
                                      const float (&gv)[8], const float (&blv)[8]) {
    const float rl = 1.f / l;
    float a[8], sum = 0.f;
    #pragma unroll
    for (int r = 0; r < 8; ++r) { a[r] = o[r] * rl; sum += a[r]; }
    sum += __shfl_xor(sum, 32);
    const float mu = sum * 0.0625f;
    float var = 0.f;
    #pragma unroll
    for (int r = 0; r < 8; ++r) { a[r] -= mu; var += a[r] * a[r]; }
    var += __shfl_xor(var, 32);
    const float inv = rsqrtf(var * 0.0625f + 1e-5f);
    float v[8];
    #pragma unroll
    for (int r = 0; r < 8; ++r) v[r] = fmaxf(a[r] * inv * gv[r] + blv[r], 0.f);
    return pk8f(v);
}

__global__ __launch_bounds__(128)
void actor_mfma(const float* __restrict__ x,
                const float* __restrict__ en_w1, const float* __restrict__ en_b1,
                const float* __restrict__ en_w2, const float* __restrict__ en_b2,
                const float* __restrict__ oa_w1, const float* __restrict__ oa_b1,
                const float* __restrict__ oa_w2, const float* __restrict__ oa_b2,
                const float* __restrict__ oa_g,  const float* __restrict__ oa_bln,
                const float* __restrict__ g_w1,  const float* __restrict__ g_b1,
                const float* __restrict__ g_w2,  const float* __restrict__ g_b2,
                const float* __restrict__ g_g,   const float* __restrict__ g_bln,
                const float* __restrict__ m_w1,  const float* __restrict__ m_b1,
                const float* __restrict__ m_w2,  const float* __restrict__ m_b2,
                const float* __restrict__ m_w3,  const float* __restrict__ m_b3,
                float* __restrict__ out, int B)
{
    const int lane = threadIdx.x & 63, wid = threadIdx.x >> 6;
    const int n = lane & 31, h = lane >> 5;

    __shared__ __align__(16) _Float16 xs[32 * XSS];
    __shared__ __align__(16) uint4 bobuf[64];

    const int r0 = blockIdx.x * 32;

    // ---- stage: wave w loads rows 16w..16w+15 ----
    {
        const int rs = r0 + 16 * wid;
        const float* __restrict__ xp = x + (size_t)rs * OBS;
        _Float16* xw = xs + 16 * wid * XSS;
        if (rs + 16 <= B) {
            #pragma unroll
            for (int i = 0; i < 8; ++i) {
                const int gI = i * 64 + lane;
                if (gI < 496) {                  // 16 rows x 31 float4
                    const int row = gI / 31;
                    const int c4 = gI - row * 31;
                    const f4u v = *(const f4u*)(xp + row * 127 + c4 * 4);
                    PK8 q;
                    q.p[0] = __builtin_amdgcn_cvt_pkrtz(v[0], v[1]);
                    q.p[1] = __builtin_amdgcn_cvt_pkrtz(v[2], v[3]);
                    *(uint2*)(xw + row * XSS + c4 * 4) = *(const uint2*)&q;
                }
            }
            if (lane < 48) {                     // tail cols 124..126
                const int row = lane / 3;
                const int c = 124 + lane - row * 3;
                xw[row * XSS + c] = (_Float16)xp[row * 127 + c];
            }
        } else if (rs < B) {
            const int lim = (B - rs) * OBS;
            for (int i = 0; i < 32; ++i) {
                const int f = i * 64 + lane;
                if (f < lim) {
                    const int r = f / 127;
                    xw[f + 5 * r] = (_Float16)xp[f];
                }
            }
        }
    }
    __syncthreads();

    v16f z16;
    #pragma unroll
    for (int r = 0; r < 16; ++r) z16[r] = 0.f;

    float sb2v[8];
    #pragma unroll
    for (int r = 0; r < 8; ++r) {
        const int m = (r & 3) + 8 * (r >> 2) + 4 * h;
        sb2v[r] = en_b2[m];
    }

    // ---- self encoder (both waves, 32 rows; needed for scores) ----
    const _Float16* xr = xs + n * XSS;
    float st[8], stl[8];
    v8h Bs;
    {
        const v8h sA1 = a1fragK16(en_w1, en_b1, 4, n, h);
        const v8h sA2a = a2fragK16(en_w2, 0, n, h);
        const v8h sA2b = a2fragK16(en_w2, 1, n, h);
        v8h bs = zero8h();
        if (h == 0) {
            HU8 u;
            #pragma unroll
            for (int j = 0; j < 4; ++j) u.u[j] = 0;
            *(uint2*)&u.u[0] = *(const uint2*)xr;   // x0..x3
            u.e[4] = (_Float16)1.f;                 // k=4 bias
            bs = u.h;
        }
        const v16f dS = MFMA16(sA1, bs, z16);
        v16f cS = MFMA16(sA2a, pkr8(dS, 0), z16);
        cS = MFMA16(sA2b, pkr8(dS, 8), cS);
        const float SK = 0.25f * 1.44269504088896f;
        float sv[8];
        #pragma unroll
        for (int r = 0; r < 8; ++r) {
            sv[r] = fmaxf(cS[r] + sb2v[r], 0.f);
            st[r] = sv[r];
            stl[r] = sv[r] * SK;
        }
        Bs = pk8f(sv);
    }

    v8h Bf = zero8h();
    if (wid == 1) {
        // ==== wave 1: other branch (15 entities, even/odd chains) ====
        const v8h oA1 = a1fragK16(oa_w1, oa_b1, 5, n, h);
        const v8h oA2a = a2fragK16(oa_w2, 0, n, h);
        const v8h oA2b = a2fragK16(oa_w2, 1, n, h);
        float ob2v[8], ogv[8], oblv[8];
        #pragma unroll
        for (int r = 0; r < 8; ++r) {
            const int m = (r & 3) + 8 * (r >> 2) + 4 * h;
            ob2v[r] = oa_b2[m];
            ogv[r] = oa_g[m]; oblv[r] = oa_bln[m];
        }
        float l0 = 0.f, l1 = 0.f, o0[8], o1[8];
        #pragma unroll
        for (int r = 0; r < 8; ++r) { o0[r] = 0.f; o1[r] = 0.f; }
        #pragma unroll 2
        for (int i = 0; i < 7; ++i) {
            entity_step<0>(xr, 2 * i,     h, oA1, oA2a, oA2b, ob2v, stl, l0, o0, z16);
            entity_step<0>(xr, 2 * i + 1, h, oA1, oA2a, oA2b, ob2v, stl, l1, o1, z16);
        }
        entity_step<0>(xr, 14, h, oA1, oA2a, oA2b, ob2v, stl, l0, o0, z16);
        l0 += l1;
        #pragma unroll
        for (int r = 0; r < 8; ++r) o0[r] += o1[r];
        BO bo;
        bo.h = ln_fin(l0, o0, ogv, oblv);
        bobuf[lane] = bo.u;
    } else {
        // ==== wave 0: food branch (16 entities, even/odd chains) ====
        const v8h fA1 = a1fragK16(g_w1, g_b1, 3, n, h);
        const v8h fA2a = a2fragK16(g_w2, 0, n, h);
        const v8h fA2b = a2fragK16(g_w2, 1, n, h);
        float fb2v[8], fgv[8], fblv[8];
        #pragma unroll
        for (int r = 0; r < 8; ++r) {
            const int m = (r & 3) + 8 * (r >> 2) + 4 * h;
            fb2v[r] = g_b2[m];
            fgv[r] = g_g[m]; fblv[r] = g_bln[m];
        }
        float l0 = 0.f, l1 = 0.f, o0[8], o1[8];
        #pragma unroll
        for (int r = 0; r < 8; ++r) { o0[r] = 0.f; o1[r] = 0.f; }
        #pragma unroll 2
        for (int i = 0; i < 8; ++i) {
            entity_step<1>(xr, 2 * i,     h, fA1, fA2a, fA2b, fb2v, stl, l0, o0, z16);
            entity_step<1>(xr, 2 * i + 1, h, fA1, fA2a, fA2b, fb2v, stl, l1, o1, z16);
        }
        l0 += l1;
        #pragma unroll
        for (int r = 0; r < 8; ++r) o0[r] += o1[r];
        Bf = ln_fin(l0, o0, fgv, fblv);
    }
    __syncthreads();

    if (wid == 0) {
        // ==== wave 0: merge MLP 48 -> 32 lrelu -> 32 lrelu -> 2 tanh ====
        BO bo;
        bo.u = bobuf[lane];
        const v8h Bo = bo.h;
        v16f m1C, m2C;
        #pragma unroll
        for (int r = 0; r < 16; ++r) {
            const int m = (r & 3) + 8 * (r >> 2) + 4 * h;
            m1C[r] = m_b1[m];
            m2C[r] = m_b2[m];
        }
        v16f m1 = MFMA16(mfragK16(m_w1, 32, 0, n, h, 32), Bs, m1C);
        m1 = MFMA16(mfragK16(m_w1, 32, 16, n, h, 32), Bf, m1);
        m1 = MFMA16(mfragK16(m_w1, 32, 32, n, h, 32), Bo, m1);
        const v8h q0 = lrelu8(pk8(m1, 0));
        const v8h q1 = lrelu8(pk8(m1, 8));
        v16f m2 = MFMA16(mfragK16(m_w2, 32, 0, n, h, 32), q0, m2C);
        m2 = MFMA16(mfragK16(m_w2, 32, 16, n, h, 32), q1, m2);
        const v8h z0 = lrelu8(pk8(m2, 0));
        const v8h z1 = lrelu8(pk8(m2, 8));
        v16f m3 = MFMA16(mfragK16(m_w3, 2, 0, n, h, 2), z0, z16);
        m3 = MFMA16(mfragK16(m_w3, 2, 16, n, h, 2), z1, m3);

        if (h == 0 && r0 + n < B) {
            float2 res;
            res.x = fast_tanh(m3[0] + m_b3[0]);
            res.y = fast_tanh(m3[1] + m_b3[1]);
            *(float2*)(out + (size_t)(r0 + n) * 2) = res;
        }
    }
}

extern "C" void kernel_launch(void* const* d_in, const int* in_sizes, int n_in,
                              void* d_out, int out_size, void* d_ws, size_t ws_size,
                              hipStream_t stream) {
    const int B = in_sizes[0] / OBS;
    const float* xin = (const float*)d_in[0];
    const float* en_w1 = (const float*)d_in[1];
    const float* en_b1 = (const float*)d_in[2];
    const float* en_w2 = (const float*)d_in[3];
    const float* en_b2 = (const float*)d_in[4];
    const float* oa_w1 = (const float*)d_in[5];
    const float* oa_b1 = (const float*)d_in[6];
    const float* oa_w2 = (const float*)d_in[7];
    const float* oa_b2 = (const float*)d_in[8];
    const float* oa_g  = (const float*)d_in[9];
    const float* oa_bl = (const float*)d_in[10];
    const float* g_w1  = (const float*)d_in[11];
    const float* g_b1  = (const float*)d_in[12];
    const float* g_w2  = (const float*)d_in[13];
    const float* g_b2  = (const float*)d_in[14];
    const float* g_g   = (const float*)d_in[15];
    const float* g_bl  = (const float*)d_in[16];
    const float* m_w1  = (const float*)d_in[17];
    const float* m_b1  = (const float*)d_in[18];
    const float* m_w2  = (const float*)d_in[19];
    const float* m_b2  = (const float*)d_in[20];
    const float* m_w3  = (const float*)d_in[21];
    const float* m_b3  = (const float*)d_in[22];

    const int grid = (B + 31) / 32;   // 2 waves per 32-row tile
    actor_mfma<<<grid, 128, 0, stream>>>(
        xin, en_w1, en_b1, en_w2, en_b2,
        oa_w1, oa_b1, oa_w2, oa_b2, oa_g, oa_bl,
        g_w1, g_b1, g_w2, g_b2, g_g, g_bl,
        m_w1, m_b1, m_w2, m_b2, m_w3, m_b3,
        (float*)d_out, B);
}